// Round 9
// baseline (152.219 us; speedup 1.0000x reference)
//
#include <hip/hip_runtime.h>
#include <hip/hip_bf16.h>

typedef __attribute__((ext_vector_type(4))) float f32x4;
typedef __attribute__((ext_vector_type(8))) short s16x8;
typedef __attribute__((ext_vector_type(4))) uint u32x4;

#define MFMA16(a, b, c) __builtin_amdgcn_mfma_f32_16x16x32_bf16(a, b, c, 0, 0, 0)

#define DG 256
#define NE 16
#define NN 17
#define TB 16      // tokens per block
#define NTOK 8192
#define PAD 260    // floats; row stride 1040 B (16B aligned), 2-way bank alias only (free)

// ws float offsets (small data)
#define WS_S    0        // Sdiv [17][256]  (= S[n]/a[n])
#define WS_AD   4376     // Ad2 dense [17*17] (= Anorm[e][m] * a[m])
#define WS_EW   8768     // exp@W1 [16][256]
// ws byte offsets (pre-swizzled bf16 weight fragments)
#define FB_WMH  65536
#define FB_W1H  1114112
#define FB_W1L  1245184
#define FB_W2H  1376256
#define WS_NEED 1638400

// ---------- scalar RNE helpers (setup + fallback only) ----------
__device__ __forceinline__ ushort bf16h(float f) {
    union { float f; uint u; } c; c.f = f;
    return (ushort)((c.u + 0x7fffu + ((c.u >> 16) & 1u)) >> 16);  // RNE
}
__device__ __forceinline__ float bf16tof(ushort h) {
    union { uint u; float f; } c; c.u = (uint)h << 16;
    return c.f;
}
__device__ __forceinline__ void cvt_hilo(f32x4 a, f32x4 b, s16x8& hi, s16x8& lo) {
#pragma unroll
    for (int i = 0; i < 4; ++i) {
        const ushort h = bf16h(a[i]);
        hi[i] = (short)h;
        lo[i] = (short)bf16h(a[i] - bf16tof(h));
    }
#pragma unroll
    for (int i = 0; i < 4; ++i) {
        const ushort h = bf16h(b[i]);
        hi[4 + i] = (short)h;
        lo[4 + i] = (short)bf16h(b[i] - bf16tof(h));
    }
}

// ---------- fast packed converter (v_cvt_pk_bf16_f32) ----------
__device__ __forceinline__ uint pkbf(float a, float b) {
    __hip_bfloat162 t = __float22bfloat162_rn(make_float2(a, b));
    return *reinterpret_cast<uint*>(&t);
}

// W fragment: elem(l,i) = W[ks*32 + 8*(l>>4) + i][nt*16 + (l&15)]
// (serves as B-operand in phases A/B, and as A-operand = W^T in phase C)
template<bool SWZ>
__device__ __forceinline__ void loadB(const ushort* __restrict__ H,
                                      const ushort* __restrict__ L,
                                      const float* __restrict__ Wf,
                                      int KST, int nt, int ks, int lane,
                                      s16x8& bh, s16x8& bl) {
    if (SWZ) {
        const size_t off = ((size_t)(nt * KST + ks) * 64 + lane) * 8;
        bh = *(const s16x8*)(H + off);
        bl = *(const s16x8*)(L + off);
    } else {
        const int k0 = ks * 32 + ((lane >> 4) << 3);
        const int col = nt * 16 + (lane & 15);
        const float* p = Wf + (size_t)k0 * DG + col;
        f32x4 v0, v1;
#pragma unroll
        for (int i = 0; i < 4; ++i) v0[i] = p[(size_t)i * DG];
#pragma unroll
        for (int i = 0; i < 4; ++i) v1[i] = p[(size_t)(4 + i) * DG];
        cvt_hilo(v0, v1, bh, bl);
    }
}

template<bool SWZ>
__device__ __forceinline__ void loadBH(const ushort* __restrict__ H,
                                       const float* __restrict__ Wf,
                                       int KST, int nt, int ks, int lane,
                                       s16x8& bh) {
    if (SWZ) {
        bh = *(const s16x8*)(H + ((size_t)(nt * KST + ks) * 64 + lane) * 8);
    } else {
        const int k0 = ks * 32 + ((lane >> 4) << 3);
        const int col = nt * 16 + (lane & 15);
        const float* p = Wf + (size_t)k0 * DG + col;
#pragma unroll
        for (int i = 0; i < 8; ++i) bh[i] = (short)bf16h(p[(size_t)i * DG]);
    }
}

// ---------------- setup kernel 1: block e -> exp[e], ew[e] = exp[e] @ W1 ----------------
__global__ __launch_bounds__(512) void k_se1(const float* __restrict__ X,
                                             const float* __restrict__ Wst,
                                             const float* __restrict__ W1,
                                             float* __restrict__ ws) {
    const int e = blockIdx.x, tid = threadIdx.x;
    const int d = tid & 255, half = tid >> 8;
    __shared__ float xr[1024];
    __shared__ float part[2][256];
    __shared__ float er[256];

    *(float2*)&xr[tid * 2] = *(const float2*)&X[e * 1024 + tid * 2];
    __syncthreads();
    float acc = 0.f;
    const int k0 = half * 512;
    for (int k = 0; k < 512; ++k)
        acc = fmaf(xr[k0 + k], Wst[(size_t)(k0 + k) * DG + d], acc);
    part[half][d] = acc;
    __syncthreads();
    if (tid < 256) er[tid] = fmaxf(part[0][tid] + part[1][tid], 0.f);
    __syncthreads();
    float a2 = 0.f;
    const int m0 = half * 128;
    for (int m = 0; m < 128; ++m)
        a2 = fmaf(er[m0 + m], W1[(size_t)(m0 + m) * DG + d], a2);
    part[half][d] = a2;
    __syncthreads();
    if (tid < 256) ws[WS_EW + e * DG + tid] = part[0][tid] + part[1][tid];
}

// ---------------- setup kernel 2: blocks 0..17 adjacency/Sdiv/Ad2; blocks 18+ swizzle ----------------
__global__ __launch_bounds__(256) void k_se2(const float* __restrict__ adj,
                                             const float* __restrict__ Wm,
                                             const float* __restrict__ W1,
                                             const float* __restrict__ W2,
                                             float* __restrict__ ws) {
    const int b = blockIdx.x, tid = threadIdx.x;
    if (b >= 18) {
        char* base = (char*)ws;
        const int base4 = ((b - 18) * 256 + tid) * 4;
#pragma unroll
        for (int j = 0; j < 4; ++j) {
            const int local = base4 + j;
            const float* W; ushort* H; ushort* L; int lo2, KST; bool wantL;
            if (local < 262144)      { W = Wm; KST = 32; lo2 = local;          H = (ushort*)(base + FB_WMH); L = nullptr; wantL = false; }
            else if (local < 327680) { W = W1; KST = 8;  lo2 = local - 262144; H = (ushort*)(base + FB_W1H); L = (ushort*)(base + FB_W1L); wantL = true; }
            else                     { W = W2; KST = 8;  lo2 = local - 327680; H = (ushort*)(base + FB_W2H); L = nullptr; wantL = false; }
            const int i = lo2 & 7, l = (lo2 >> 3) & 63, t = lo2 >> 9;
            const int ks = t % KST, nt = t / KST;
            const int k = ks * 32 + ((l >> 4) << 3) + i;
            const int col = nt * 16 + (l & 15);
            const float wv = W[(size_t)k * DG + col];
            const ushort h = bf16h(wv);
            H[lo2] = h;
            if (wantL) L[lo2] = bf16h(wv - bf16tof(h));
        }
        return;
    }
    __shared__ float dinv[NN];
    __shared__ float row[NN];
    if (tid < NN) {
        float deg = 0.f;
        for (int m = 0; m < NN; ++m) deg += adj[tid * NN + m];
        dinv[tid] = 1.0f / sqrtf(deg);
    }
    __syncthreads();
    if (b < NN) {
        if (tid < NN) row[tid] = adj[b * NN + tid] * dinv[b] * dinv[tid];
        __syncthreads();
        float s = 0.f;
        for (int e = 0; e < NE; ++e) s = fmaf(row[e], ws[WS_EW + e * DG + tid], s);
        // store S / a[b],  a[b] = dinv[b]*dinv[16] > 0 (hub column all-ones)
        const float ab = dinv[b] * dinv[16];
        ws[WS_S + b * DG + tid] = s / ab;
    } else {
        // Ad2[r][c] = Anorm[r][c] * a[c] = adj*dinv[r]*dinv[c] * dinv[c]*dinv[16]
        for (int i = tid; i < NN * NN; i += 256) {
            const int r = i / NN, c = i % NN;
            ws[WS_AD + i] = adj[i] * dinv[r] * dinv[c] * dinv[c] * dinv[16];
        }
    }
}

// ---------------- fused main kernel: TB=16, 1024 thr, 16 waves, barrier-free phase C ----------------
template<bool SWZ>
__global__ __launch_bounds__(1024) void k_main(
        const float* __restrict__ x,
        const float* __restrict__ Wm,
        const float* __restrict__ W1,
        const float* __restrict__ W2,
        const float* __restrict__ Wp,
        const float* __restrict__ ws,
        float* __restrict__ out) {
    const int tid = threadIdx.x;
    const int lane = tid & 63, w = tid >> 6;          // wave = d-col-tile 0..15
    const int r16 = lane & 15, g4 = lane >> 4;
    const size_t t0 = (size_t)blockIdx.x * TB;

    __shared__ float S_s[NN][PAD];                    // 17680 B (Sdiv)
    __shared__ float g_s[TB][PAD];                    // 16640 B
    __shared__ alignas(16) union {
        ushort xs[2][8][64][8];                       // 16384 B (x frags, dbuf)
        struct { ushort H[8][64][8]; ushort L[8][64][8]; } hf;  // h frags
    } U1;
    __shared__ float part[NE][16][17];                // 17408 B [e][t][w]
    __shared__ float Ad_l[NN * NN];

    // staging map: thread -> (row, 4-float segment) of the 16x256 x-chunk
    const int srow = tid >> 6;                        // 0..15
    const int sseg = tid & 63;                        // 4-float segment
    const int sk8 = sseg >> 3;
    const int so  = (sseg * 4) & 31;
    const int sl  = ((so >> 3) << 4) | srow;
    const int si  = so & 7;                           // 0 or 4

    for (int j = tid; j < NN * DG; j += 1024) S_s[j >> 8][j & 255] = ws[WS_S + j];
    for (int j = tid; j < NN * NN; j += 1024) Ad_l[j] = ws[WS_AD + j];

    const char* base = (const char*)ws;
    const ushort* WmH = (const ushort*)(base + FB_WMH);
    const ushort* W1H = (const ushort*)(base + FB_W1H);
    const ushort* W1L = (const ushort*)(base + FB_W1L);
    const ushort* W2H = (const ushort*)(base + FB_W2H);

    // stage x chunk 0 (single bf16, convert-once)
    {
        const f32x4 v = *(const f32x4*)&x[(t0 + srow) * 1024 + sseg * 4];
        uint2 uu = make_uint2(pkbf(v[0], v[1]), pkbf(v[2], v[3]));
        *(uint2*)&U1.xs[0][sk8][sl][si] = uu;
    }
    __syncthreads();

    // ---- phase A: h = relu(x @ Wm), x & Wm single-bf16, 4 chunks, dbuf ----
    f32x4 hacc = (f32x4){0.f, 0.f, 0.f, 0.f};
    for (int c = 0; c < 4; ++c) {
        f32x4 xn;
        if (c < 3)
            xn = *(const f32x4*)&x[(t0 + srow) * 1024 + (c + 1) * 256 + sseg * 4];
        for (int k8 = 0; k8 < 8; ++k8) {
            s16x8 bh;
            loadBH<SWZ>(WmH, Wm, 32, w, c * 8 + k8, lane, bh);
            const s16x8 ah = *(const s16x8*)&U1.xs[c & 1][k8][lane][0];
            hacc = MFMA16(ah, bh, hacc);
        }
        if (c < 3) {
            uint2 uu = make_uint2(pkbf(xn[0], xn[1]), pkbf(xn[2], xn[3]));
            *(uint2*)&U1.xs[(c + 1) & 1][sk8][sl][si] = uu;
        }
        __syncthreads();
    }

    // write h (relu) as hi/lo MFMA A-fragments into hf (xs dead, post-barrier)
    {
        const int k8h = w >> 1;
        const int o = ((w & 1) << 4) | r16;
        const int lb = (o >> 3) << 4;
        const int ih = o & 7;
        const float hv0 = fmaxf(hacc[0], 0.f), hv1 = fmaxf(hacc[1], 0.f);
        const float hv2 = fmaxf(hacc[2], 0.f), hv3 = fmaxf(hacc[3], 0.f);
        const uint p01 = pkbf(hv0, hv1), p23 = pkbf(hv2, hv3);
        union { uint u; float f; } b0, b1, b2, b3;
        b0.u = p01 << 16; b1.u = p01 & 0xffff0000u;
        b2.u = p23 << 16; b3.u = p23 & 0xffff0000u;
        const uint q01 = pkbf(hv0 - b0.f, hv1 - b1.f);
        const uint q23 = pkbf(hv2 - b2.f, hv3 - b3.f);
        const int r0 = g4 * 4;
        U1.hf.H[k8h][lb + r0 + 0][ih] = (ushort)p01;
        U1.hf.H[k8h][lb + r0 + 1][ih] = (ushort)(p01 >> 16);
        U1.hf.H[k8h][lb + r0 + 2][ih] = (ushort)p23;
        U1.hf.H[k8h][lb + r0 + 3][ih] = (ushort)(p23 >> 16);
        U1.hf.L[k8h][lb + r0 + 0][ih] = (ushort)q01;
        U1.hf.L[k8h][lb + r0 + 1][ih] = (ushort)(q01 >> 16);
        U1.hf.L[k8h][lb + r0 + 2][ih] = (ushort)q23;
        U1.hf.L[k8h][lb + r0 + 3][ih] = (ushort)(q23 >> 16);
    }
    __syncthreads();

    // ---- phase B: g = h @ W1 (h hi/lo, W1 hi/lo), K=256 ----
    f32x4 gacc = (f32x4){0.f, 0.f, 0.f, 0.f};
    for (int k8 = 0; k8 < 8; ++k8) {
        s16x8 bh, bl;
        loadB<SWZ>(W1H, W1L, W1, 8, w, k8, lane, bh, bl);
        const s16x8 ah = *(const s16x8*)&U1.hf.H[k8][lane][0];
        const s16x8 aL = *(const s16x8*)&U1.hf.L[k8][lane][0];
        gacc = MFMA16(ah, bh, gacc);
        gacc = MFMA16(aL, bh, gacc);
        gacc = MFMA16(ah, bl, gacc);
    }
#pragma unroll
    for (int r = 0; r < 4; ++r)
        g_s[g4 * 4 + r][w * 16 + r16] = gacc[r];
    __syncthreads();   // g_s ready; S_s/g_s now read-only -> phase C barrier-free

    // ---- phase C: z^T = W2^T @ y1^T, in-lane B-frag build, NO barriers ----
    // A-operand = stored W2 frag (same bytes); B-frag lane l: y1r[t=l&15][k0..k0+7],
    // y1r = relu(g + Sdiv[n]); scale a[n] folded into Ad2 (phase E).
    f32x4 acc[NN];
#pragma unroll
    for (int n = 0; n < NN; ++n) acc[n] = (f32x4){0.f, 0.f, 0.f, 0.f};

    const int kg = (lane >> 4) << 3;
    for (int ks = 0; ks < 8; ++ks) {
        s16x8 aW;
        loadBH<SWZ>(W2H, W2, 8, w, ks, lane, aW);
        const int k0 = ks * 32 + kg;
        const f32x4 G0 = *(const f32x4*)&g_s[r16][k0];
        const f32x4 G1 = *(const f32x4*)&g_s[r16][k0 + 4];
#pragma unroll
        for (int n = 0; n < NN; ++n) {
            const f32x4 Sa = *(const f32x4*)&S_s[n][k0];
            const f32x4 Sb = *(const f32x4*)&S_s[n][k0 + 4];
            float y0 = fmaxf(G0[0] + Sa[0], 0.f), y1v = fmaxf(G0[1] + Sa[1], 0.f);
            float y2 = fmaxf(G0[2] + Sa[2], 0.f), y3 = fmaxf(G0[3] + Sa[3], 0.f);
            float y4 = fmaxf(G1[0] + Sb[0], 0.f), y5 = fmaxf(G1[1] + Sb[1], 0.f);
            float y6 = fmaxf(G1[2] + Sb[2], 0.f), y7 = fmaxf(G1[3] + Sb[3], 0.f);
            u32x4 uu;
            uu[0] = pkbf(y0, y1v);
            uu[1] = pkbf(y2, y3);
            uu[2] = pkbf(y4, y5);
            uu[3] = pkbf(y6, y7);
            const s16x8 bf = __builtin_bit_cast(s16x8, uu);
            acc[n] = MFMA16(aW, bf, acc[n]);
        }
    }

    // ---- phase E: y2 = relu(Ad2 @ z); score = y2 . Wp ----
    // thread holds z[token=r16][d = w*16 + g4*4 + r]; d-reduce = 4 in-thread + 2 shfl
    float wp4[4];
#pragma unroll
    for (int r = 0; r < 4; ++r) wp4[r] = Wp[w * 16 + g4 * 4 + r];

    for (int e = 0; e < NE; ++e) {
        f32x4 z = (f32x4){0.f, 0.f, 0.f, 0.f};
#pragma unroll
        for (int m = 0; m < NN; ++m) {
            const float av = Ad_l[e * NN + m];
            if (av != 0.f) {   // uniform branch; Ad2 is sparse
#pragma unroll
                for (int r = 0; r < 4; ++r) z[r] = fmaf(av, acc[m][r], z[r]);
            }
        }
        float v = 0.f;
#pragma unroll
        for (int r = 0; r < 4; ++r) v += fmaxf(z[r], 0.f) * wp4[r];
        v += __shfl_xor(v, 16, 64);
        v += __shfl_xor(v, 32, 64);
        if (lane < 16) part[e][lane][w] = v;
    }
    __syncthreads();
    if (tid < 256) {
        const int t = tid >> 4, e = tid & 15;
        float s2 = 0.f;
#pragma unroll
        for (int q = 0; q < 16; ++q) s2 += part[e][t][q];
        out[(t0 + t) * NE + e] = s2;
    }
}

extern "C" void kernel_launch(void* const* d_in, const int* in_sizes, int n_in,
                              void* d_out, int out_size, void* d_ws, size_t ws_size,
                              hipStream_t stream) {
    const float* x   = (const float*)d_in[0];
    const float* X   = (const float*)d_in[1];
    const float* Wm  = (const float*)d_in[2];
    const float* Wst = (const float*)d_in[3];
    const float* Wc  = (const float*)d_in[4];
    const float* Wp  = (const float*)d_in[5];
    const float* adj = (const float*)d_in[6];
    float* out = (float*)d_out;
    float* ws  = (float*)d_ws;
    const float* W1 = Wc;
    const float* W2 = Wc + DG * DG;

    k_se1<<<NE, 512, 0, stream>>>(X, Wst, W1, ws);

    if (ws_size >= (size_t)WS_NEED) {
        k_se2<<<18 + 384, 256, 0, stream>>>(adj, Wm, W1, W2, ws);
        k_main<true><<<NTOK / TB, 1024, 0, stream>>>(x, Wm, W1, W2, Wp, ws, out);
    } else {
        k_se2<<<18, 256, 0, stream>>>(adj, Wm, W1, W2, ws);
        k_main<false><<<NTOK / TB, 1024, 0, stream>>>(x, Wm, W1, W2, Wp, ws, out);
    }
}

// Round 10
// 125.542 us; speedup vs baseline: 1.2125x; 1.2125x over previous
//
#include <hip/hip_runtime.h>
#include <hip/hip_bf16.h>

typedef __attribute__((ext_vector_type(4))) float f32x4;
typedef __attribute__((ext_vector_type(8))) short s16x8;
typedef __attribute__((ext_vector_type(4))) uint u32x4;

#define MFMA16(a, b, c) __builtin_amdgcn_mfma_f32_16x16x32_bf16(a, b, c, 0, 0, 0)

#define DG 256
#define NE 16
#define NN 17
#define TB 16      // tokens per block
#define NTOK 8192
#define PAD 260    // floats; row stride 1040 B (16B aligned), 2-way bank alias only (free)

// ws float offsets (small data)
#define WS_S    0        // Sdiv [17][256]  (= S[n]/a[n])
#define WS_AD   4376     // Ad2 dense [17*17] (= Anorm[e][m] * a[m])
#define WS_EW   8768     // exp@W1 [16][256]
// ws byte offsets (pre-swizzled bf16 weight fragments)
#define FB_WMH  65536
#define FB_W1H  1114112
#define FB_W1L  1245184
#define FB_W2H  1376256
#define WS_NEED 1638400

// ---------- scalar RNE helpers (setup + fallback only) ----------
__device__ __forceinline__ ushort bf16h(float f) {
    union { float f; uint u; } c; c.f = f;
    return (ushort)((c.u + 0x7fffu + ((c.u >> 16) & 1u)) >> 16);  // RNE
}
__device__ __forceinline__ float bf16tof(ushort h) {
    union { uint u; float f; } c; c.u = (uint)h << 16;
    return c.f;
}
__device__ __forceinline__ void cvt_hilo(f32x4 a, f32x4 b, s16x8& hi, s16x8& lo) {
#pragma unroll
    for (int i = 0; i < 4; ++i) {
        const ushort h = bf16h(a[i]);
        hi[i] = (short)h;
        lo[i] = (short)bf16h(a[i] - bf16tof(h));
    }
#pragma unroll
    for (int i = 0; i < 4; ++i) {
        const ushort h = bf16h(b[i]);
        hi[4 + i] = (short)h;
        lo[4 + i] = (short)bf16h(b[i] - bf16tof(h));
    }
}

// ---------- fast packed converter (v_cvt_pk_bf16_f32) ----------
__device__ __forceinline__ uint pkbf(float a, float b) {
    __hip_bfloat162 t = __float22bfloat162_rn(make_float2(a, b));
    return *reinterpret_cast<uint*>(&t);
}

// W fragment: elem(l,i) = W[ks*32 + 8*(l>>4) + i][nt*16 + (l&15)]
template<bool SWZ>
__device__ __forceinline__ void loadB(const ushort* __restrict__ H,
                                      const ushort* __restrict__ L,
                                      const float* __restrict__ Wf,
                                      int KST, int nt, int ks, int lane,
                                      s16x8& bh, s16x8& bl) {
    if (SWZ) {
        const size_t off = ((size_t)(nt * KST + ks) * 64 + lane) * 8;
        bh = *(const s16x8*)(H + off);
        bl = *(const s16x8*)(L + off);
    } else {
        const int k0 = ks * 32 + ((lane >> 4) << 3);
        const int col = nt * 16 + (lane & 15);
        const float* p = Wf + (size_t)k0 * DG + col;
        f32x4 v0, v1;
#pragma unroll
        for (int i = 0; i < 4; ++i) v0[i] = p[(size_t)i * DG];
#pragma unroll
        for (int i = 0; i < 4; ++i) v1[i] = p[(size_t)(4 + i) * DG];
        cvt_hilo(v0, v1, bh, bl);
    }
}

template<bool SWZ>
__device__ __forceinline__ void loadBH(const ushort* __restrict__ H,
                                       const float* __restrict__ Wf,
                                       int KST, int nt, int ks, int lane,
                                       s16x8& bh) {
    if (SWZ) {
        bh = *(const s16x8*)(H + ((size_t)(nt * KST + ks) * 64 + lane) * 8);
    } else {
        const int k0 = ks * 32 + ((lane >> 4) << 3);
        const int col = nt * 16 + (lane & 15);
        const float* p = Wf + (size_t)k0 * DG + col;
#pragma unroll
        for (int i = 0; i < 8; ++i) bh[i] = (short)bf16h(p[(size_t)i * DG]);
    }
}

// ---------------- setup kernel 1: block e -> exp[e], ew[e] = exp[e] @ W1 ----------------
__global__ __launch_bounds__(512) void k_se1(const float* __restrict__ X,
                                             const float* __restrict__ Wst,
                                             const float* __restrict__ W1,
                                             float* __restrict__ ws) {
    const int e = blockIdx.x, tid = threadIdx.x;
    const int d = tid & 255, half = tid >> 8;
    __shared__ float xr[1024];
    __shared__ float part[2][256];
    __shared__ float er[256];

    *(float2*)&xr[tid * 2] = *(const float2*)&X[e * 1024 + tid * 2];
    __syncthreads();
    float acc = 0.f;
    const int k0 = half * 512;
    for (int k = 0; k < 512; ++k)
        acc = fmaf(xr[k0 + k], Wst[(size_t)(k0 + k) * DG + d], acc);
    part[half][d] = acc;
    __syncthreads();
    if (tid < 256) er[tid] = fmaxf(part[0][tid] + part[1][tid], 0.f);
    __syncthreads();
    float a2 = 0.f;
    const int m0 = half * 128;
    for (int m = 0; m < 128; ++m)
        a2 = fmaf(er[m0 + m], W1[(size_t)(m0 + m) * DG + d], a2);
    part[half][d] = a2;
    __syncthreads();
    if (tid < 256) ws[WS_EW + e * DG + tid] = part[0][tid] + part[1][tid];
}

// ---------------- setup kernel 2: blocks 0..17 adjacency/Sdiv/Ad2; blocks 18+ swizzle ----------------
__global__ __launch_bounds__(256) void k_se2(const float* __restrict__ adj,
                                             const float* __restrict__ Wm,
                                             const float* __restrict__ W1,
                                             const float* __restrict__ W2,
                                             float* __restrict__ ws) {
    const int b = blockIdx.x, tid = threadIdx.x;
    if (b >= 18) {
        char* base = (char*)ws;
        const int base4 = ((b - 18) * 256 + tid) * 4;
#pragma unroll
        for (int j = 0; j < 4; ++j) {
            const int local = base4 + j;
            const float* W; ushort* H; ushort* L; int lo2, KST; bool wantL;
            if (local < 262144)      { W = Wm; KST = 32; lo2 = local;          H = (ushort*)(base + FB_WMH); L = nullptr; wantL = false; }
            else if (local < 327680) { W = W1; KST = 8;  lo2 = local - 262144; H = (ushort*)(base + FB_W1H); L = (ushort*)(base + FB_W1L); wantL = true; }
            else                     { W = W2; KST = 8;  lo2 = local - 327680; H = (ushort*)(base + FB_W2H); L = nullptr; wantL = false; }
            const int i = lo2 & 7, l = (lo2 >> 3) & 63, t = lo2 >> 9;
            const int ks = t % KST, nt = t / KST;
            const int k = ks * 32 + ((l >> 4) << 3) + i;
            const int col = nt * 16 + (l & 15);
            const float wv = W[(size_t)k * DG + col];
            const ushort h = bf16h(wv);
            H[lo2] = h;
            if (wantL) L[lo2] = bf16h(wv - bf16tof(h));
        }
        return;
    }
    __shared__ float dinv[NN];
    __shared__ float row[NN];
    if (tid < NN) {
        float deg = 0.f;
        for (int m = 0; m < NN; ++m) deg += adj[tid * NN + m];
        dinv[tid] = 1.0f / sqrtf(deg);
    }
    __syncthreads();
    if (b < NN) {
        if (tid < NN) row[tid] = adj[b * NN + tid] * dinv[b] * dinv[tid];
        __syncthreads();
        float s = 0.f;
        for (int e = 0; e < NE; ++e) s = fmaf(row[e], ws[WS_EW + e * DG + tid], s);
        const float ab = dinv[b] * dinv[16];   // a[b] > 0 (hub column all-ones)
        ws[WS_S + b * DG + tid] = s / ab;
    } else {
        for (int i = tid; i < NN * NN; i += 256) {
            const int r = i / NN, c = i % NN;
            ws[WS_AD + i] = adj[i] * dinv[r] * dinv[c] * dinv[c] * dinv[16];
        }
    }
}

// ---------------- fused main: 512 thr, 8 waves; grid = token-tiles x 2 col-halves ----------------
// 2 blocks/CU (LDS 79.5 KB, regs <=128): cross-block overlap hides barriers.
template<bool SWZ>
__global__ __launch_bounds__(512, 4) void k_main(
        const float* __restrict__ x,
        const float* __restrict__ Wm,
        const float* __restrict__ W1,
        const float* __restrict__ W2,
        const float* __restrict__ Wp,
        const float* __restrict__ ws,
        float* __restrict__ out) {
    const int tid = threadIdx.x;
    const int lane = tid & 63, w = tid >> 6;          // wave 0..7
    const int r16 = lane & 15, g4 = lane >> 4;
    const int half = blockIdx.x & 1;                  // column half
    const size_t t0 = (size_t)(blockIdx.x >> 1) * TB;
    const int dt = half * 8 + w;                      // wave's global d-tile (phase C)

    __shared__ float S_s[NN][PAD];                    // 17680 B (Sdiv)
    __shared__ float g_s[TB][PAD];                    // 16640 B
    __shared__ alignas(16) union {
        ushort xs[2][8][64][8];                       // 16384 B (x frags, dbuf)
        struct { ushort H[8][64][8]; ushort L[8][64][8]; } hf;  // 16384 B (h frags)
        ushort frag[2][NN * 64 * 8];                  // 34816 B (y1 dbuf, phase C)
    } U1;
    __shared__ float part[16][16][9];                 // 9216 B [t][e][w + pad]
    __shared__ float Ad_l[NN * NN];                   // 1156 B

    // staging map: thread -> (row, 8-float segment) of the 16x256 x-chunk
    const int srow = tid >> 5;                        // 0..15
    const int s8 = tid & 31;                          // 8-float segment in row
    const int sk8 = s8 >> 2;
    const int sl = ((s8 & 3) << 4) | srow;

    for (int j = tid; j < NN * DG; j += 512) S_s[j >> 8][j & 255] = ws[WS_S + j];
    for (int j = tid; j < NN * NN; j += 512) Ad_l[j] = ws[WS_AD + j];

    const char* base = (const char*)ws;
    const ushort* WmH = (const ushort*)(base + FB_WMH);
    const ushort* W1H = (const ushort*)(base + FB_W1H);
    const ushort* W1L = (const ushort*)(base + FB_W1L);
    const ushort* W2H = (const ushort*)(base + FB_W2H);

    // stage x chunk 0 (single bf16, convert-once; 8 floats/thread)
    {
        const float* px = &x[(t0 + srow) * 1024 + s8 * 8];
        const f32x4 v0 = *(const f32x4*)px;
        const f32x4 v1 = *(const f32x4*)(px + 4);
        u32x4 uu;
        uu[0] = pkbf(v0[0], v0[1]); uu[1] = pkbf(v0[2], v0[3]);
        uu[2] = pkbf(v1[0], v1[1]); uu[3] = pkbf(v1[2], v1[3]);
        *(u32x4*)&U1.xs[0][sk8][sl][0] = uu;
    }
    __syncthreads();

    // ---- phase A: h = relu(x @ Wm) FULL N=256 (wave w -> col tiles 2w, 2w+1) ----
    f32x4 hacc[2];
    hacc[0] = (f32x4){0.f, 0.f, 0.f, 0.f};
    hacc[1] = (f32x4){0.f, 0.f, 0.f, 0.f};
    for (int c = 0; c < 4; ++c) {
        f32x4 xn0, xn1;
        if (c < 3) {
            const float* px = &x[(t0 + srow) * 1024 + (c + 1) * 256 + s8 * 8];
            xn0 = *(const f32x4*)px;
            xn1 = *(const f32x4*)(px + 4);
        }
        for (int k8 = 0; k8 < 8; ++k8) {
            s16x8 bh0, bh1;
            loadBH<SWZ>(WmH, Wm, 32, 2 * w,     c * 8 + k8, lane, bh0);
            loadBH<SWZ>(WmH, Wm, 32, 2 * w + 1, c * 8 + k8, lane, bh1);
            const s16x8 ah = *(const s16x8*)&U1.xs[c & 1][k8][lane][0];
            hacc[0] = MFMA16(ah, bh0, hacc[0]);
            hacc[1] = MFMA16(ah, bh1, hacc[1]);
        }
        if (c < 3) {   // write next chunk into the other buffer (dbuf-safe)
            u32x4 uu;
            uu[0] = pkbf(xn0[0], xn0[1]); uu[1] = pkbf(xn0[2], xn0[3]);
            uu[2] = pkbf(xn1[0], xn1[1]); uu[3] = pkbf(xn1[2], xn1[3]);
            *(u32x4*)&U1.xs[(c + 1) & 1][sk8][sl][0] = uu;
        }
        __syncthreads();
    }

    // write h (relu) as hi/lo MFMA A-fragments (xs dead now, post-barrier)
#pragma unroll
    for (int j = 0; j < 2; ++j) {
        const int c2 = 2 * w + j;
        const int k8h = c2 >> 1;
        const int o = ((c2 & 1) << 4) | r16;
        const int lb = (o >> 3) << 4;
        const int ih = o & 7;
        const float hv0 = fmaxf(hacc[j][0], 0.f), hv1 = fmaxf(hacc[j][1], 0.f);
        const float hv2 = fmaxf(hacc[j][2], 0.f), hv3 = fmaxf(hacc[j][3], 0.f);
        const uint p01 = pkbf(hv0, hv1), p23 = pkbf(hv2, hv3);
        union { uint u; float f; } b0, b1, b2, b3;
        b0.u = p01 << 16; b1.u = p01 & 0xffff0000u;
        b2.u = p23 << 16; b3.u = p23 & 0xffff0000u;
        const uint q01 = pkbf(hv0 - b0.f, hv1 - b1.f);
        const uint q23 = pkbf(hv2 - b2.f, hv3 - b3.f);
        const int r0 = g4 * 4;
        U1.hf.H[k8h][lb + r0 + 0][ih] = (ushort)p01;
        U1.hf.H[k8h][lb + r0 + 1][ih] = (ushort)(p01 >> 16);
        U1.hf.H[k8h][lb + r0 + 2][ih] = (ushort)p23;
        U1.hf.H[k8h][lb + r0 + 3][ih] = (ushort)(p23 >> 16);
        U1.hf.L[k8h][lb + r0 + 0][ih] = (ushort)q01;
        U1.hf.L[k8h][lb + r0 + 1][ih] = (ushort)(q01 >> 16);
        U1.hf.L[k8h][lb + r0 + 2][ih] = (ushort)q23;
        U1.hf.L[k8h][lb + r0 + 3][ih] = (ushort)(q23 >> 16);
    }
    __syncthreads();

    // ---- phase B: g = h @ W1 FULL N=256 (h hi/lo, W1 hi/lo) ----
    f32x4 gacc[2];
    gacc[0] = (f32x4){0.f, 0.f, 0.f, 0.f};
    gacc[1] = (f32x4){0.f, 0.f, 0.f, 0.f};
    for (int k8 = 0; k8 < 8; ++k8) {
        s16x8 bh0, bl0, bh1, bl1;
        loadB<SWZ>(W1H, W1L, W1, 8, 2 * w,     k8, lane, bh0, bl0);
        loadB<SWZ>(W1H, W1L, W1, 8, 2 * w + 1, k8, lane, bh1, bl1);
        const s16x8 ah = *(const s16x8*)&U1.hf.H[k8][lane][0];
        const s16x8 aL = *(const s16x8*)&U1.hf.L[k8][lane][0];
        gacc[0] = MFMA16(ah, bh0, gacc[0]);
        gacc[0] = MFMA16(aL, bh0, gacc[0]);
        gacc[0] = MFMA16(ah, bl0, gacc[0]);
        gacc[1] = MFMA16(ah, bh1, gacc[1]);
        gacc[1] = MFMA16(aL, bh1, gacc[1]);
        gacc[1] = MFMA16(ah, bl1, gacc[1]);
    }
#pragma unroll
    for (int j = 0; j < 2; ++j)
#pragma unroll
        for (int r = 0; r < 4; ++r)
            g_s[g4 * 4 + r][(2 * w + j) * 16 + r16] = gacc[j][r];
    __syncthreads();   // g_s ready; hf reads done (frag overlays next)

    // ---- phase C: layer-2 GEMM for this block's 8 d-tiles; shared dbuf build, 1 barrier/ks ----
    f32x4 acc[NN];
#pragma unroll
    for (int n = 0; n < NN; ++n) acc[n] = (f32x4){0.f, 0.f, 0.f, 0.f};

    const int kg = (lane >> 4) << 3;
    for (int ks = 0; ks < 8; ++ks) {
        // prefetch W2 A-side... (B-operand for this wave's d-tile)
        s16x8 bh;
        loadBH<SWZ>(W2H, W2, 8, dt, ks, lane, bh);

        // build y1r = relu(g + Sdiv[n]) fragments; wave w -> nodes w, w+8, (+16 for wave 0)
        {
            ushort* fr = U1.frag[ks & 1];
            const int k0 = ks * 32 + kg;
            const f32x4 G0 = *(const f32x4*)&g_s[r16][k0];
            const f32x4 G1 = *(const f32x4*)&g_s[r16][k0 + 4];
            const int nlist[3] = { w, w + 8, 16 };
            const int ncnt = (w == 0) ? 3 : 2;
            for (int q = 0; q < ncnt; ++q) {
                const int n = nlist[q];
                const f32x4 Sa = *(const f32x4*)&S_s[n][k0];
                const f32x4 Sb = *(const f32x4*)&S_s[n][k0 + 4];
                u32x4 uu;
                uu[0] = pkbf(fmaxf(G0[0] + Sa[0], 0.f), fmaxf(G0[1] + Sa[1], 0.f));
                uu[1] = pkbf(fmaxf(G0[2] + Sa[2], 0.f), fmaxf(G0[3] + Sa[3], 0.f));
                uu[2] = pkbf(fmaxf(G1[0] + Sb[0], 0.f), fmaxf(G1[1] + Sb[1], 0.f));
                uu[3] = pkbf(fmaxf(G1[2] + Sb[2], 0.f), fmaxf(G1[3] + Sb[3], 0.f));
                *(u32x4*)&fr[(size_t)(n * 64 + lane) * 8] = uu;
            }
        }
        __syncthreads();   // frag[ks&1] ready (dbuf: 1 barrier/ks is hazard-safe)

        const ushort* fb = U1.frag[ks & 1];
        __builtin_amdgcn_s_setprio(1);
#pragma unroll
        for (int n = 0; n < NN; ++n) {
            const s16x8 ah = *(const s16x8*)&fb[(n * 64 + lane) * 8];
            acc[n] = MFMA16(ah, bh, acc[n]);
        }
        __builtin_amdgcn_s_setprio(0);
    }

    // ---- phase E: y2 = relu(Ad2 @ z); partial score over this half's d-range ----
    // thread holds z[token = g4*4+r][d = dt*16 + r16]
    const float wp = Wp[dt * 16 + r16];
    for (int e = 0; e < NE; ++e) {
        f32x4 z = (f32x4){0.f, 0.f, 0.f, 0.f};
#pragma unroll
        for (int m = 0; m < NN; ++m) {
            const float av = Ad_l[e * NN + m];
            if (av != 0.f) {   // uniform branch; Ad2 sparse
#pragma unroll
                for (int r = 0; r < 4; ++r) z[r] = fmaf(av, acc[m][r], z[r]);
            }
        }
        float v[4];
#pragma unroll
        for (int r = 0; r < 4; ++r) v[r] = fmaxf(z[r], 0.f) * wp;
#pragma unroll
        for (int off = 1; off < 16; off <<= 1)
#pragma unroll
            for (int r = 0; r < 4; ++r) v[r] += __shfl_xor(v[r], off, 64);
        if (r16 == 0)
#pragma unroll
            for (int r = 0; r < 4; ++r) part[g4 * 4 + r][e][w] = v[r];
    }
    __syncthreads();
    if (tid < 256) {
        const int t = tid >> 4, e = tid & 15;
        float s2 = 0.f;
#pragma unroll
        for (int q = 0; q < 8; ++q) s2 += part[t][e][q];
        atomicAdd(&out[(t0 + t) * NE + e], s2);   // two halves sum; f32 add commutative
    }
}

extern "C" void kernel_launch(void* const* d_in, const int* in_sizes, int n_in,
                              void* d_out, int out_size, void* d_ws, size_t ws_size,
                              hipStream_t stream) {
    const float* x   = (const float*)d_in[0];
    const float* X   = (const float*)d_in[1];
    const float* Wm  = (const float*)d_in[2];
    const float* Wst = (const float*)d_in[3];
    const float* Wc  = (const float*)d_in[4];
    const float* Wp  = (const float*)d_in[5];
    const float* adj = (const float*)d_in[6];
    float* out = (float*)d_out;
    float* ws  = (float*)d_ws;
    const float* W1 = Wc;
    const float* W2 = Wc + DG * DG;

    hipMemsetAsync(out, 0, (size_t)out_size * sizeof(float), stream);
    k_se1<<<NE, 512, 0, stream>>>(X, Wst, W1, ws);

    if (ws_size >= (size_t)WS_NEED) {
        k_se2<<<18 + 384, 256, 0, stream>>>(adj, Wm, W1, W2, ws);
        k_main<true><<<(NTOK / TB) * 2, 512, 0, stream>>>(x, Wm, W1, W2, Wp, ws, out);
    } else {
        k_se2<<<18, 256, 0, stream>>>(adj, Wm, W1, W2, ws);
        k_main<false><<<(NTOK / TB) * 2, 512, 0, stream>>>(x, Wm, W1, W2, Wp, ws, out);
    }
}

// Round 11
// 96.456 us; speedup vs baseline: 1.5781x; 1.3015x over previous
//
#include <hip/hip_runtime.h>
#include <hip/hip_bf16.h>

typedef __attribute__((ext_vector_type(4))) float f32x4;
typedef __attribute__((ext_vector_type(8))) short s16x8;
typedef __attribute__((ext_vector_type(4))) uint u32x4;

#define MFMA16(a, b, c) __builtin_amdgcn_mfma_f32_16x16x32_bf16(a, b, c, 0, 0, 0)

#define DG 256
#define NE 16
#define NN 17
#define TB 16      // tokens per block
#define NTOK 8192
#define PAD 260    // floats; row stride 1040 B (16B aligned)

// ws float offsets (small data)
#define WS_S    0        // Sdiv [17][256]  (= S[n]/a[n])
#define WS_AD   4376     // Ad2 dense [17*17] (= Anorm[e][m] * a[m])
#define WS_MSK  4704     // nonzero masks [16] (uint bits over m)
#define WS_EW   8768     // exp@W1 [16][256]
// ws byte offsets (pre-swizzled bf16 weight fragments)
#define FB_WMH  65536
#define FB_W1H  1114112
#define FB_W1L  1245184
#define FB_W2H  1376256
#define WS_NEED 1638400

// ---------- scalar RNE helpers ----------
__device__ __forceinline__ ushort bf16h(float f) {
    union { float f; uint u; } c; c.f = f;
    return (ushort)((c.u + 0x7fffu + ((c.u >> 16) & 1u)) >> 16);  // RNE
}
__device__ __forceinline__ float bf16tof(ushort h) {
    union { uint u; float f; } c; c.u = (uint)h << 16;
    return c.f;
}
__device__ __forceinline__ void cvt_hilo(f32x4 a, f32x4 b, s16x8& hi, s16x8& lo) {
#pragma unroll
    for (int i = 0; i < 4; ++i) {
        const ushort h = bf16h(a[i]);
        hi[i] = (short)h;
        lo[i] = (short)bf16h(a[i] - bf16tof(h));
    }
#pragma unroll
    for (int i = 0; i < 4; ++i) {
        const ushort h = bf16h(b[i]);
        hi[4 + i] = (short)h;
        lo[4 + i] = (short)bf16h(b[i] - bf16tof(h));
    }
}

// ---------- fast packed converter (v_cvt_pk_bf16_f32) ----------
__device__ __forceinline__ uint pkbf(float a, float b) {
    __hip_bfloat162 t = __float22bfloat162_rn(make_float2(a, b));
    return *reinterpret_cast<uint*>(&t);
}

// W fragment: elem(l,i) = W[ks*32 + 8*(l>>4) + i][nt*16 + (l&15)]
template<bool SWZ>
__device__ __forceinline__ void loadB(const ushort* __restrict__ H,
                                      const ushort* __restrict__ L,
                                      const float* __restrict__ Wf,
                                      int KST, int nt, int ks, int lane,
                                      s16x8& bh, s16x8& bl) {
    if (SWZ) {
        const size_t off = ((size_t)(nt * KST + ks) * 64 + lane) * 8;
        bh = *(const s16x8*)(H + off);
        bl = *(const s16x8*)(L + off);
    } else {
        const int k0 = ks * 32 + ((lane >> 4) << 3);
        const int col = nt * 16 + (lane & 15);
        const float* p = Wf + (size_t)k0 * DG + col;
        f32x4 v0, v1;
#pragma unroll
        for (int i = 0; i < 4; ++i) v0[i] = p[(size_t)i * DG];
#pragma unroll
        for (int i = 0; i < 4; ++i) v1[i] = p[(size_t)(4 + i) * DG];
        cvt_hilo(v0, v1, bh, bl);
    }
}

template<bool SWZ>
__device__ __forceinline__ void loadBH(const ushort* __restrict__ H,
                                       const float* __restrict__ Wf,
                                       int KST, int nt, int ks, int lane,
                                       s16x8& bh) {
    if (SWZ) {
        bh = *(const s16x8*)(H + ((size_t)(nt * KST + ks) * 64 + lane) * 8);
    } else {
        const int k0 = ks * 32 + ((lane >> 4) << 3);
        const int col = nt * 16 + (lane & 15);
        const float* p = Wf + (size_t)k0 * DG + col;
#pragma unroll
        for (int i = 0; i < 8; ++i) bh[i] = (short)bf16h(p[(size_t)i * DG]);
    }
}

// -------- setup 1: blocks 0-15 expert path; blocks 16+ weight swizzle (parallel) --------
__global__ __launch_bounds__(512) void k_se1(const float* __restrict__ X,
                                             const float* __restrict__ Wst,
                                             const float* __restrict__ W1,
                                             const float* __restrict__ Wm,
                                             const float* __restrict__ W2,
                                             float* __restrict__ ws) {
    const int b = blockIdx.x, tid = threadIdx.x;
    if (b >= 16) {
        char* base = (char*)ws;
        const int base4 = (b - 16) * 2048 + tid * 4;
#pragma unroll
        for (int j = 0; j < 4; ++j) {
            const int local = base4 + j;
            const float* W; ushort* H; ushort* L; int lo2, KST; bool wantL;
            if (local < 262144)      { W = Wm; KST = 32; lo2 = local;          H = (ushort*)(base + FB_WMH); L = nullptr; wantL = false; }
            else if (local < 327680) { W = W1; KST = 8;  lo2 = local - 262144; H = (ushort*)(base + FB_W1H); L = (ushort*)(base + FB_W1L); wantL = true; }
            else                     { W = W2; KST = 8;  lo2 = local - 327680; H = (ushort*)(base + FB_W2H); L = nullptr; wantL = false; }
            const int i = lo2 & 7, l = (lo2 >> 3) & 63, t = lo2 >> 9;
            const int ks = t % KST, nt = t / KST;
            const int k = ks * 32 + ((l >> 4) << 3) + i;
            const int col = nt * 16 + (l & 15);
            const float wv = W[(size_t)k * DG + col];
            const ushort h = bf16h(wv);
            H[lo2] = h;
            if (wantL) L[lo2] = bf16h(wv - bf16tof(h));
        }
        return;
    }
    const int e = b;
    const int d = tid & 255, half = tid >> 8;
    __shared__ float xr[1024];
    __shared__ float part[2][256];
    __shared__ float er[256];

    *(float2*)&xr[tid * 2] = *(const float2*)&X[e * 1024 + tid * 2];
    __syncthreads();
    float acc = 0.f;
    const int k0 = half * 512;
    for (int k = 0; k < 512; ++k)
        acc = fmaf(xr[k0 + k], Wst[(size_t)(k0 + k) * DG + d], acc);
    part[half][d] = acc;
    __syncthreads();
    if (tid < 256) er[tid] = fmaxf(part[0][tid] + part[1][tid], 0.f);
    __syncthreads();
    float a2 = 0.f;
    const int m0 = half * 128;
    for (int m = 0; m < 128; ++m)
        a2 = fmaf(er[m0 + m], W1[(size_t)(m0 + m) * DG + d], a2);
    part[half][d] = a2;
    __syncthreads();
    if (tid < 256) ws[WS_EW + e * DG + tid] = part[0][tid] + part[1][tid];
}

// -------- setup 2 (18 blocks): 0-16 Sdiv rows; 17: Ad2 dense + nonzero masks --------
__global__ __launch_bounds__(256) void k_se2(const float* __restrict__ adj,
                                             float* __restrict__ ws) {
    const int b = blockIdx.x, tid = threadIdx.x;
    __shared__ float dinv[NN];
    __shared__ float row[NN];
    __shared__ float Ad_sh[NN * NN];
    if (tid < NN) {
        float deg = 0.f;
        for (int m = 0; m < NN; ++m) deg += adj[tid * NN + m];
        dinv[tid] = 1.0f / sqrtf(deg);
    }
    __syncthreads();
    if (b < NN) {
        if (tid < NN) row[tid] = adj[b * NN + tid] * dinv[b] * dinv[tid];
        __syncthreads();
        float s = 0.f;
        for (int e = 0; e < NE; ++e) s = fmaf(row[e], ws[WS_EW + e * DG + tid], s);
        const float ab = dinv[b] * dinv[16];   // a[b] > 0 (hub column all-ones)
        ws[WS_S + b * DG + tid] = s / ab;
    } else {
        // Ad2[r][c] = adj*dinv[r]*dinv[c] * (dinv[c]*dinv[16])
        for (int i = tid; i < NN * NN; i += 256) {
            const int r = i / NN, c = i % NN;
            Ad_sh[i] = adj[i] * dinv[r] * dinv[c] * dinv[c] * dinv[16];
        }
        __syncthreads();
        for (int i = tid; i < NN * NN; i += 256) ws[WS_AD + i] = Ad_sh[i];
        if (tid < NE) {
            uint m = 0;
            for (int c = 0; c < NN; ++c)
                if (Ad_sh[tid * NN + c] != 0.f) m |= (1u << c);
            ((uint*)(ws))[WS_MSK + tid] = m;
        }
    }
}

// -------- fused main: TB=16, 1024 thr, 16 waves; dbuf phase C (1 barrier/ks) --------
template<bool SWZ>
__global__ __launch_bounds__(1024) void k_main(
        const float* __restrict__ x,
        const float* __restrict__ Wm,
        const float* __restrict__ W1,
        const float* __restrict__ W2,
        const float* __restrict__ Wp,
        const float* __restrict__ ws,
        float* __restrict__ out) {
    const int tid = threadIdx.x;
    const int lane = tid & 63, w = tid >> 6;          // wave = d-col-tile 0..15
    const int r16 = lane & 15, g4 = lane >> 4;
    const size_t t0 = (size_t)blockIdx.x * TB;

    __shared__ float S_s[NN][PAD];                    // 17680 B (Sdiv)
    __shared__ float g_s[TB][PAD];                    // 16640 B
    __shared__ alignas(16) union {
        ushort xs[2][8][64][8];                       // 16384 B (x frags, dbuf)
        struct { ushort H[8][64][8]; ushort L[8][64][8]; } hf;  // h frags
    } U1;
    __shared__ alignas(16) union {
        ushort frag[2][NN * 64 * 8];                  // 34816 B (y1 dbuf)
        float part[16][16][17];                       // 17408 B (aliases frag[0] only)
    } U2;
    __shared__ float Ad_l[NN * NN];

    // staging map: thread -> (row, 4-float segment) of the 16x256 x-chunk
    const int srow = tid >> 6;                        // 0..15
    const int sseg = tid & 63;
    const int sk8 = sseg >> 3;
    const int so  = (sseg * 4) & 31;
    const int sl  = ((so >> 3) << 4) | srow;
    const int si  = so & 7;                           // 0 or 4

    for (int j = tid; j < NN * DG; j += 1024) S_s[j >> 8][j & 255] = ws[WS_S + j];
    for (int j = tid; j < NN * NN; j += 1024) Ad_l[j] = ws[WS_AD + j];

    // hoist nonzero masks into SGPRs (uniform): scalar branches in phase E
    uint msk[NE];
#pragma unroll
    for (int e = 0; e < NE; ++e)
        msk[e] = __builtin_amdgcn_readfirstlane(((const uint*)ws)[WS_MSK + e]);

    const char* base = (const char*)ws;
    const ushort* WmH = (const ushort*)(base + FB_WMH);
    const ushort* W1H = (const ushort*)(base + FB_W1H);
    const ushort* W1L = (const ushort*)(base + FB_W1L);
    const ushort* W2H = (const ushort*)(base + FB_W2H);

    // stage x chunk 0 (single bf16, convert-once)
    {
        const f32x4 v = *(const f32x4*)&x[(t0 + srow) * 1024 + sseg * 4];
        uint2 uu = make_uint2(pkbf(v[0], v[1]), pkbf(v[2], v[3]));
        *(uint2*)&U1.xs[0][sk8][sl][si] = uu;
    }
    __syncthreads();

    // ---- phase A: h = relu(x @ Wm), x & Wm single-bf16, 4 chunks, dbuf ----
    f32x4 hacc = (f32x4){0.f, 0.f, 0.f, 0.f};
    for (int c = 0; c < 4; ++c) {
        f32x4 xn;
        if (c < 3)
            xn = *(const f32x4*)&x[(t0 + srow) * 1024 + (c + 1) * 256 + sseg * 4];
        for (int k8 = 0; k8 < 8; ++k8) {
            s16x8 bh;
            loadBH<SWZ>(WmH, Wm, 32, w, c * 8 + k8, lane, bh);
            const s16x8 ah = *(const s16x8*)&U1.xs[c & 1][k8][lane][0];
            hacc = MFMA16(ah, bh, hacc);
        }
        if (c < 3) {
            uint2 uu = make_uint2(pkbf(xn[0], xn[1]), pkbf(xn[2], xn[3]));
            *(uint2*)&U1.xs[(c + 1) & 1][sk8][sl][si] = uu;
        }
        __syncthreads();
    }

    // write h (relu) as hi/lo MFMA A-fragments (xs dead, post-barrier)
    {
        const int k8h = w >> 1;
        const int o = ((w & 1) << 4) | r16;
        const int lb = (o >> 3) << 4;
        const int ih = o & 7;
        const float hv0 = fmaxf(hacc[0], 0.f), hv1 = fmaxf(hacc[1], 0.f);
        const float hv2 = fmaxf(hacc[2], 0.f), hv3 = fmaxf(hacc[3], 0.f);
        const uint p01 = pkbf(hv0, hv1), p23 = pkbf(hv2, hv3);
        union { uint u; float f; } b0, b1, b2, b3;
        b0.u = p01 << 16; b1.u = p01 & 0xffff0000u;
        b2.u = p23 << 16; b3.u = p23 & 0xffff0000u;
        const uint q01 = pkbf(hv0 - b0.f, hv1 - b1.f);
        const uint q23 = pkbf(hv2 - b2.f, hv3 - b3.f);
        const int r0 = g4 * 4;
        U1.hf.H[k8h][lb + r0 + 0][ih] = (ushort)p01;
        U1.hf.H[k8h][lb + r0 + 1][ih] = (ushort)(p01 >> 16);
        U1.hf.H[k8h][lb + r0 + 2][ih] = (ushort)p23;
        U1.hf.H[k8h][lb + r0 + 3][ih] = (ushort)(p23 >> 16);
        U1.hf.L[k8h][lb + r0 + 0][ih] = (ushort)q01;
        U1.hf.L[k8h][lb + r0 + 1][ih] = (ushort)(q01 >> 16);
        U1.hf.L[k8h][lb + r0 + 2][ih] = (ushort)q23;
        U1.hf.L[k8h][lb + r0 + 3][ih] = (ushort)(q23 >> 16);
    }
    __syncthreads();

    // ---- phase B: g = h @ W1 (h hi/lo, W1 hi/lo), K=256 ----
    f32x4 gacc = (f32x4){0.f, 0.f, 0.f, 0.f};
    for (int k8 = 0; k8 < 8; ++k8) {
        s16x8 bh, bl;
        loadB<SWZ>(W1H, W1L, W1, 8, w, k8, lane, bh, bl);
        const s16x8 ah = *(const s16x8*)&U1.hf.H[k8][lane][0];
        const s16x8 aL = *(const s16x8*)&U1.hf.L[k8][lane][0];
        gacc = MFMA16(ah, bh, gacc);
        gacc = MFMA16(aL, bh, gacc);
        gacc = MFMA16(ah, bl, gacc);
    }
#pragma unroll
    for (int r = 0; r < 4; ++r)
        g_s[g4 * 4 + r][w * 16 + r16] = gacc[r];
    __syncthreads();   // g_s ready; hf reads done (frag overlays next)

    // ---- phase C: layer-2 GEMM; y1r = relu(g + Sdiv[n]); dbuf, 1 barrier/ks ----
    f32x4 acc[NN];
#pragma unroll
    for (int n = 0; n < NN; ++n) acc[n] = (f32x4){0.f, 0.f, 0.f, 0.f};

    for (int ks = 0; ks < 8; ++ks) {
        s16x8 bh;
        loadBH<SWZ>(W2H, W2, 8, w, ks, lane, bh);

        ushort* fr = U2.frag[ks & 1];
        auto build_slot = [&](int s) {
            const int n = s >> 6, l = s & 63;
            const int row = l & 15;
            const int k0 = ks * 32 + ((l >> 4) << 3);
            const f32x4 G0 = *(const f32x4*)&g_s[row][k0];
            const f32x4 G1 = *(const f32x4*)&g_s[row][k0 + 4];
            const f32x4 Sa = *(const f32x4*)&S_s[n][k0];
            const f32x4 Sb = *(const f32x4*)&S_s[n][k0 + 4];
            u32x4 uu;
            uu[0] = pkbf(fmaxf(G0[0] + Sa[0], 0.f), fmaxf(G0[1] + Sa[1], 0.f));
            uu[1] = pkbf(fmaxf(G0[2] + Sa[2], 0.f), fmaxf(G0[3] + Sa[3], 0.f));
            uu[2] = pkbf(fmaxf(G1[0] + Sb[0], 0.f), fmaxf(G1[1] + Sb[1], 0.f));
            uu[3] = pkbf(fmaxf(G1[2] + Sb[2], 0.f), fmaxf(G1[3] + Sb[3], 0.f));
            *(u32x4*)&fr[(size_t)s * 8] = uu;
        };
        build_slot(tid);
        if (tid < NN * 64 - 1024) build_slot(tid + 1024);
        __syncthreads();   // frag[ks&1] ready; dbuf makes one barrier/ks hazard-safe

        const ushort* fb = U2.frag[ks & 1];
        __builtin_amdgcn_s_setprio(1);
#pragma unroll
        for (int n = 0; n < NN; ++n) {
            const s16x8 ah = *(const s16x8*)&fb[(n * 64 + lane) * 8];
            acc[n] = MFMA16(ah, bh, acc[n]);
        }
        __builtin_amdgcn_s_setprio(0);
    }
    // NOTE: last ks=7 reads frag[1]; part below aliases frag[0] only -> no hazard.

    // ---- phase E: y2 = relu(Ad2 @ z); score = y2 . Wp; masked scan + pair butterfly ----
    const float wp = Wp[w * 16 + r16];
    const bool b0 = (r16 & 1) != 0;
#pragma unroll
    for (int p = 0; p < 8; ++p) {
        f32x4 v2[2];
#pragma unroll
        for (int j = 0; j < 2; ++j) {
            const int e = 2 * p + j;
            f32x4 z = (f32x4){0.f, 0.f, 0.f, 0.f};
#pragma unroll
            for (int m = 0; m < NN; ++m) {
                if (msk[e] & (1u << m)) {          // SGPR test -> scalar branch
                    const float av = Ad_l[e * NN + m];
#pragma unroll
                    for (int r = 0; r < 4; ++r) z[r] = fmaf(av, acc[m][r], z[r]);
                }
            }
#pragma unroll
            for (int r = 0; r < 4; ++r) v2[j][r] = fmaxf(z[r], 0.f) * wp;
        }
        // stage 1 over e-parity (lane bit 0)
        f32x4 wv;
#pragma unroll
        for (int r = 0; r < 4; ++r) {
            const float keep = b0 ? v2[1][r] : v2[0][r];
            const float send = b0 ? v2[0][r] : v2[1][r];
            wv[r] = keep + __shfl_xor(send, 1, 64);
        }
        // finish lane reduction over bits 1,2,3 of r16
#pragma unroll
        for (int r = 0; r < 4; ++r) wv[r] += __shfl_xor(wv[r], 2, 64);
#pragma unroll
        for (int r = 0; r < 4; ++r) wv[r] += __shfl_xor(wv[r], 4, 64);
#pragma unroll
        for (int r = 0; r < 4; ++r) wv[r] += __shfl_xor(wv[r], 8, 64);
        if (r16 < 2)
#pragma unroll
            for (int r = 0; r < 4; ++r) U2.part[g4 * 4 + r][2 * p + r16][w] = wv[r];
    }
    __syncthreads();
    if (tid < 256) {
        const int t = tid >> 4, e = tid & 15;
        float s2 = 0.f;
#pragma unroll
        for (int q = 0; q < 16; ++q) s2 += U2.part[t][e][q];
        out[(t0 + t) * NE + e] = s2;
    }
}

extern "C" void kernel_launch(void* const* d_in, const int* in_sizes, int n_in,
                              void* d_out, int out_size, void* d_ws, size_t ws_size,
                              hipStream_t stream) {
    const float* x   = (const float*)d_in[0];
    const float* X   = (const float*)d_in[1];
    const float* Wm  = (const float*)d_in[2];
    const float* Wst = (const float*)d_in[3];
    const float* Wc  = (const float*)d_in[4];
    const float* Wp  = (const float*)d_in[5];
    const float* adj = (const float*)d_in[6];
    float* out = (float*)d_out;
    float* ws  = (float*)d_ws;
    const float* W1 = Wc;
    const float* W2 = Wc + DG * DG;

    if (ws_size >= (size_t)WS_NEED) {
        k_se1<<<16 + 192, 512, 0, stream>>>(X, Wst, W1, Wm, W2, ws);
        k_se2<<<18, 256, 0, stream>>>(adj, ws);
        k_main<true><<<NTOK / TB, 1024, 0, stream>>>(x, Wm, W1, W2, Wp, ws, out);
    } else {
        k_se1<<<16, 512, 0, stream>>>(X, Wst, W1, Wm, W2, ws);
        k_se2<<<18, 256, 0, stream>>>(adj, ws);
        k_main<false><<<NTOK / TB, 1024, 0, stream>>>(x, Wm, W1, W2, Wp, ws, out);
    }
}